// Round 10
// baseline (85.244 us; speedup 1.0000x reference)
//
#include <hip/hip_runtime.h>

#define BATCH 2048
#define ODIM 64
#define IDIM 64
#define MDIM 32

static constexpr float LOG2E = 1.4426950408889634f;

#if __has_builtin(__builtin_amdgcn_exp2f)
#define EXP2F(x) __builtin_amdgcn_exp2f(x)
#else
#define EXP2F(x) exp2f(x)
#endif

typedef float v2f __attribute__((ext_vector_type(2)));

// Fully fused: block = one o x 256 b's, 512 thr / 8 waves; lane owns 4 b's
// (two <2 x float> groups) so each broadcast constant read serves 256 b.
//
// psi_m = A*2^{a(x-z_m)^2} = [A*2^{a z_m^2}] * Ebase * r^m,
//   Ebase = 2^{x(e1 x + e2)}, r = 2^{rc x};  e1=a, e2=-2a z0, rc=-2a dz.
// em_i = Ebase * P(r),  ev_i = Ebase^2 * Q(r^2)   (P,Q: 32-coeff polys,
// Horner with even/odd splits: 4 pk-fma per 2 m per group).
//
// x is staged in 4 chunks of 16 i (16 KB) to keep LDS at 33 KB; per chunk
// wave w handles i = 16c+w and 16c+8+w. The x-chunk LDS is reused as the
// cross-wave reduction buffer at the end.
__global__ __launch_bounds__(512, 8) void gpkan_fused_kernel(
    const float* __restrict__ x, const float* __restrict__ z,
    const float* __restrict__ q_mu, const float* __restrict__ q_log_var,
    const float* __restrict__ log_scale, const float* __restrict__ log_variance,
    float* __restrict__ out)
{
    const int o     = blockIdx.x & (ODIM - 1);
    const int btile = blockIdx.x >> 6;                        // 0..7
    const int tid   = threadIdx.x;
    const int lane  = tid & 63;
    const int wave  = __builtin_amdgcn_readfirstlane(tid >> 6); // 0..7

    __shared__ float2 lcm[IDIM * MDIM];   // 16 KB
    __shared__ float4 laux[IDIM];         // 1 KB
    __shared__ float  xchunk[16][256];    // 16 KB; reused as reduction buffer

    // ---- Phase A: per-m constants for this o (4 elements / thread) ----
    #pragma unroll
    for (int k = 0; k < 4; ++k) {
        int e  = tid + 512 * k;                      // in [0, I*M)
        int i  = e >> 5;
        int oi = o * IDIM + i;
        int g  = oi * MDIM + (e & (MDIM - 1));

        float ls   = log_scale[oi];
        float lv   = log_variance[oi];
        float ell  = fmaxf(expf(ls), 0.1f);
        float ell2 = ell * ell;
        float vk   = fmaxf(expf(lv), 1e-5f);
        float denom = ell2 + 1e-6f;                  // x_var is constant EPS_XVAR
        float A    = vk * sqrtf(ell2 / denom);
        float a    = -0.5f * LOG2E / denom;          // base-2 exponent scale

        float qm = q_mu[g];
        float qv = fmaxf(expf(q_log_var[g]), 1e-5f);
        float zm = z[g];
        float w  = exp2f(a * zm * zm);

        float2 c;
        c.x = A * qm * w;                            // c1~
        c.y = A * A * (qv + qm * qm) * w * w;        // c2~
        lcm[e] = c;
    }
    if (tid < IDIM) {
        int oi = o * IDIM + tid;
        float ls   = log_scale[oi];
        float ell  = fmaxf(expf(ls), 0.1f);
        float denom = ell * ell + 1e-6f;
        float a    = -0.5f * LOG2E / denom;
        float z0 = z[oi * MDIM + 0];
        float z1 = z[oi * MDIM + 1];
        float dz = z1 - z0;
        laux[tid] = make_float4(a, -2.0f * a * z0, -2.0f * a * dz, 0.0f);
    }

    v2f emtA = {0.f, 0.f}, evtA = {0.f, 0.f};
    v2f emtB = {0.f, 0.f}, evtB = {0.f, 0.f};

    // ---- chunked i-loop: 4 chunks of 16 i ----
    const int row = tid >> 1;                 // 0..255 (b within tile)
    const int colh = (tid & 1) * 2;           // which float4 pair of the chunk
    #pragma unroll 1
    for (int c = 0; c < 4; ++c) {
        __syncthreads();                      // previous chunk fully consumed
        // stage x chunk: i in [16c, 16c+16) for 256 b (2 float4 per thread)
        {
            const float4* xr =
                (const float4*)(x + (size_t)(btile * 256 + row) * IDIM + 16 * c);
            #pragma unroll
            for (int j = 0; j < 2; ++j) {
                float4 v = xr[colh + j];
                int ib = 4 * (colh + j);
                xchunk[ib + 0][row] = v.x;
                xchunk[ib + 1][row] = v.y;
                xchunk[ib + 2][row] = v.z;
                xchunk[ib + 3][row] = v.w;
            }
        }
        __syncthreads();

        // this wave's 2 i's in the chunk
        #pragma unroll
        for (int h = 0; h < 2; ++h) {
            const int li = wave + 8 * h;      // local i (0..15)
            const int gi = 16 * c + li;       // global i

            v2f xvA, xvB;
            xvA.x = xchunk[li][lane];
            xvA.y = xchunk[li][lane + 64];
            xvB.x = xchunk[li][lane + 128];
            xvB.y = xchunk[li][lane + 192];

            const float4 Ax = laux[gi];
            v2f e1 = {Ax.x, Ax.x}, e2 = {Ax.y, Ax.y}, rc = {Ax.z, Ax.z};

            v2f tA = __builtin_elementwise_fma(e1, xvA, e2) * xvA;
            v2f tB = __builtin_elementwise_fma(e1, xvB, e2) * xvB;
            v2f EbA, EbB;
            EbA.x = EXP2F(tA.x); EbA.y = EXP2F(tA.y);
            EbB.x = EXP2F(tB.x); EbB.y = EXP2F(tB.y);
            v2f uA = rc * xvA, uB = rc * xvB;
            v2f rA, rB;
            rA.x = EXP2F(uA.x); rA.y = EXP2F(uA.y);
            rB.x = EXP2F(uB.x); rB.y = EXP2F(uB.y);

            v2f sA = rA * rA, sB = rB * rB;   // r^2
            v2f uuA = sA * sA, uuB = sB * sB; // r^4

            v2f PeA = {0.f, 0.f}, PoA = {0.f, 0.f};
            v2f QeA = {0.f, 0.f}, QoA = {0.f, 0.f};
            v2f PeB = {0.f, 0.f}, PoB = {0.f, 0.f};
            v2f QeB = {0.f, 0.f}, QoB = {0.f, 0.f};

            const float4* C = (const float4*)&lcm[gi * MDIM];
            #pragma unroll
            for (int k = 15; k >= 0; --k) {
                float4 cc = C[k];   // {c1_2k, c2_2k, c1_2k+1, c2_2k+1}
                v2f c1e = {cc.x, cc.x}, c2e = {cc.y, cc.y};
                v2f c1o = {cc.z, cc.z}, c2o = {cc.w, cc.w};
                PeA = __builtin_elementwise_fma(PeA, sA, c1e);
                PoA = __builtin_elementwise_fma(PoA, sA, c1o);
                QeA = __builtin_elementwise_fma(QeA, uuA, c2e);
                QoA = __builtin_elementwise_fma(QoA, uuA, c2o);
                PeB = __builtin_elementwise_fma(PeB, sB, c1e);
                PoB = __builtin_elementwise_fma(PoB, sB, c1o);
                QeB = __builtin_elementwise_fma(QeB, uuB, c2e);
                QoB = __builtin_elementwise_fma(QoB, uuB, c2o);
            }

            v2f PA = __builtin_elementwise_fma(rA, PoA, PeA);
            v2f QA = __builtin_elementwise_fma(sA, QoA, QeA);
            v2f PB = __builtin_elementwise_fma(rB, PoB, PeB);
            v2f QB = __builtin_elementwise_fma(sB, QoB, QeB);

            v2f emA = EbA * PA;
            v2f evA = (EbA * EbA) * QA;
            v2f emB = EbB * PB;
            v2f evB = (EbB * EbB) * QB;

            // clamp per (b,o,i), BEFORE the i-sum
            v2f eps = {1e-6f, 1e-6f};
            v2f dA = __builtin_elementwise_fma(-emA, emA, evA);
            v2f dB = __builtin_elementwise_fma(-emB, emB, evB);
            evtA += __builtin_elementwise_max(dA, eps);
            evtB += __builtin_elementwise_max(dB, eps);
            emtA += emA;
            emtB += emB;
        }
    }

    // ---- Phase C: reduce across waves, reusing xchunk as scratch ----
    __syncthreads();
    float* red  = &xchunk[0][0];      // em: [wave][q][lane], 2048 floats
    float* redv = red + 2048;         // ev: [wave][q][lane], 2048 floats
    red [(wave * 4 + 0) * 64 + lane] = emtA.x;
    red [(wave * 4 + 1) * 64 + lane] = emtA.y;
    red [(wave * 4 + 2) * 64 + lane] = emtB.x;
    red [(wave * 4 + 3) * 64 + lane] = emtB.y;
    redv[(wave * 4 + 0) * 64 + lane] = evtA.x;
    redv[(wave * 4 + 1) * 64 + lane] = evtA.y;
    redv[(wave * 4 + 2) * 64 + lane] = evtB.x;
    redv[(wave * 4 + 3) * 64 + lane] = evtB.y;
    __syncthreads();

    {
        const int sel = tid >> 8;         // 0: means, 1: vars
        const int q   = (tid >> 6) & 3;   // b quadrant
        const int l   = tid & 63;
        const int bb  = btile * 256 + q * 64 + l;
        float s = 0.f;
        if (sel == 0) {
            #pragma unroll
            for (int w = 0; w < 8; ++w) s += red[(w * 4 + q) * 64 + l];
            out[bb * ODIM + o] = s;                    // edge_means.sum(axis=2)
        } else {
            #pragma unroll
            for (int w = 0; w < 8; ++w) s += redv[(w * 4 + q) * 64 + l];
            out[BATCH * ODIM + bb * ODIM + o] = s;     // edge_vars.sum(axis=2)
        }
    }
}

extern "C" void kernel_launch(void* const* d_in, const int* in_sizes, int n_in,
                              void* d_out, int out_size, void* d_ws, size_t ws_size,
                              hipStream_t stream) {
    const float* x            = (const float*)d_in[0];
    const float* z            = (const float*)d_in[1];
    const float* q_mu         = (const float*)d_in[2];
    const float* q_log_var    = (const float*)d_in[3];
    const float* log_scale    = (const float*)d_in[4];
    const float* log_variance = (const float*)d_in[5];
    float* out = (float*)d_out;

    gpkan_fused_kernel<<<dim3((BATCH / 256) * ODIM), dim3(512), 0, stream>>>(
        x, z, q_mu, q_log_var, log_scale, log_variance, out);
}

// Round 11
// 83.764 us; speedup vs baseline: 1.0177x; 1.0177x over previous
//
#include <hip/hip_runtime.h>

#define BATCH 2048
#define ODIM 64
#define IDIM 64
#define MDIM 32

static constexpr float LOG2E = 1.4426950408889634f;

#if __has_builtin(__builtin_amdgcn_exp2f)
#define EXP2F(x) __builtin_amdgcn_exp2f(x)
#else
#define EXP2F(x) exp2f(x)
#endif

typedef float v2f __attribute__((ext_vector_type(2)));

// Fully fused: block = one o x 128 b's (btile 0..15), 512 thr / 8 waves.
// Lane owns b-pair (2*lane, 2*lane+1) -> single ds_read_b64 per x fetch.
//
// psi_m = A*2^{a(x-z_m)^2} = [A*2^{a z_m^2}] * Ebase * r^m,
//   Ebase = 2^{x(e1 x + e2)}, r = 2^{rc x};  e1=a, e2=-2a z0, rc=-2a dz.
// em_i = Ebase * P(r),  ev_i = Ebase^2 * Q(r^2); P,Q Horner (even/odd split).
// i-loop unrolled x2: two independent Horner streams overlap each other's
// LDS-read + exp2 serial head with the other's chain latency.
__global__ __launch_bounds__(512, 6) void gpkan_fused_kernel(
    const float* __restrict__ x, const float* __restrict__ z,
    const float* __restrict__ q_mu, const float* __restrict__ q_log_var,
    const float* __restrict__ log_scale, const float* __restrict__ log_variance,
    float* __restrict__ out)
{
    const int o     = blockIdx.x & (ODIM - 1);
    const int btile = blockIdx.x >> 6;                        // 0..15
    const int tid   = threadIdx.x;
    const int lane  = tid & 63;
    const int wave  = __builtin_amdgcn_readfirstlane(tid >> 6); // 0..7

    __shared__ float  xtile[IDIM][128];   // 32 KB; reused as reduction buffer
    __shared__ float2 lcm[IDIM * MDIM];   // 16 KB
    __shared__ float4 laux[IDIM];         // 1 KB

    // ---- Phase A.1: x-tile (coalesced 16B global loads, scatter to LDS) ----
    {
        const int bl = tid >> 2;                     // 0..127
        const int q4 = tid & 3;                      // 16-i quarter
        const float4* xr =
            (const float4*)(x + (size_t)(btile * 128 + bl) * IDIM + 16 * q4);
        #pragma unroll
        for (int j = 0; j < 4; ++j) {
            float4 v = xr[j];
            int ib = 16 * q4 + 4 * j;
            xtile[ib + 0][bl] = v.x;
            xtile[ib + 1][bl] = v.y;
            xtile[ib + 2][bl] = v.z;
            xtile[ib + 3][bl] = v.w;
        }
    }

    // ---- Phase A.2: per-m constants, 4 consecutive m per thread ----
    {
        const int e0 = tid * 4;                      // in [0, I*M), same i
        const int i  = e0 >> 5;
        const int oi = o * IDIM + i;

        float ls   = log_scale[oi];
        float lv   = log_variance[oi];
        float ell  = fmaxf(expf(ls), 0.1f);
        float ell2 = ell * ell;
        float vk   = fmaxf(expf(lv), 1e-5f);
        float denom = ell2 + 1e-6f;                  // x_var is constant EPS_XVAR
        float A    = vk * sqrtf(ell2 / denom);
        float a    = -0.5f * LOG2E / denom;          // base-2 exponent scale

        #pragma unroll
        for (int k = 0; k < 4; ++k) {
            int g  = oi * MDIM + (e0 & (MDIM - 1)) + k;
            float qm = q_mu[g];
            float qv = fmaxf(expf(q_log_var[g]), 1e-5f);
            float zm = z[g];
            float w  = exp2f(a * zm * zm);
            float2 c;
            c.x = A * qm * w;                        // c1~
            c.y = A * A * (qv + qm * qm) * w * w;    // c2~
            lcm[e0 + k] = c;
        }
        if ((e0 & 31) == 0) {                        // once per i
            float z0 = z[oi * MDIM + 0];
            float z1 = z[oi * MDIM + 1];
            float dz = z1 - z0;
            laux[i] = make_float4(a, -2.0f * a * z0, -2.0f * a * dz, 0.0f);
        }
    }
    __syncthreads();

    // ---- Phase B: Horner, i-loop unrolled x2 ----
    const int i0 = wave * 8;
    v2f emt = {0.f, 0.f};
    v2f evt = {0.f, 0.f};

    #pragma unroll 1
    for (int ii = 0; ii < 8; ii += 2) {
        const int ga = i0 + ii;
        const int gb = i0 + ii + 1;

        v2f xa = ((const v2f*)&xtile[ga][0])[lane];  // ds_read_b64
        v2f xb = ((const v2f*)&xtile[gb][0])[lane];

        const float4 Aa = laux[ga];
        const float4 Ab = laux[gb];

        v2f e1a = {Aa.x, Aa.x}, e2a = {Aa.y, Aa.y}, rca = {Aa.z, Aa.z};
        v2f e1b = {Ab.x, Ab.x}, e2b = {Ab.y, Ab.y}, rcb = {Ab.z, Ab.z};

        v2f tA = __builtin_elementwise_fma(e1a, xa, e2a) * xa;
        v2f tB = __builtin_elementwise_fma(e1b, xb, e2b) * xb;
        v2f uA = rca * xa;
        v2f uB = rcb * xb;

        v2f EbA, EbB, rA, rB;
        EbA.x = EXP2F(tA.x); EbA.y = EXP2F(tA.y);
        rA.x  = EXP2F(uA.x); rA.y  = EXP2F(uA.y);
        EbB.x = EXP2F(tB.x); EbB.y = EXP2F(tB.y);
        rB.x  = EXP2F(uB.x); rB.y  = EXP2F(uB.y);

        v2f sA = rA * rA, sB = rB * rB;     // r^2  (P chains)
        v2f wA = sA * sA, wB = sB * sB;     // r^4  (Q chains)

        v2f PeA = {0.f, 0.f}, PoA = {0.f, 0.f};
        v2f QeA = {0.f, 0.f}, QoA = {0.f, 0.f};
        v2f PeB = {0.f, 0.f}, PoB = {0.f, 0.f};
        v2f QeB = {0.f, 0.f}, QoB = {0.f, 0.f};

        const float4* CA = (const float4*)&lcm[ga * MDIM];
        const float4* CB = (const float4*)&lcm[gb * MDIM];
        #pragma unroll
        for (int k = 15; k >= 0; --k) {
            float4 ca = CA[k];   // {c1_2k, c2_2k, c1_2k+1, c2_2k+1}
            float4 cb = CB[k];
            v2f c1eA = {ca.x, ca.x}, c2eA = {ca.y, ca.y};
            v2f c1oA = {ca.z, ca.z}, c2oA = {ca.w, ca.w};
            v2f c1eB = {cb.x, cb.x}, c2eB = {cb.y, cb.y};
            v2f c1oB = {cb.z, cb.z}, c2oB = {cb.w, cb.w};

            PeA = __builtin_elementwise_fma(PeA, sA, c1eA);
            PoA = __builtin_elementwise_fma(PoA, sA, c1oA);
            QeA = __builtin_elementwise_fma(QeA, wA, c2eA);
            QoA = __builtin_elementwise_fma(QoA, wA, c2oA);
            PeB = __builtin_elementwise_fma(PeB, sB, c1eB);
            PoB = __builtin_elementwise_fma(PoB, sB, c1oB);
            QeB = __builtin_elementwise_fma(QeB, wB, c2eB);
            QoB = __builtin_elementwise_fma(QoB, wB, c2oB);
        }

        v2f PA = __builtin_elementwise_fma(rA, PoA, PeA);   // P(r)
        v2f QA = __builtin_elementwise_fma(sA, QoA, QeA);   // Q(r^2)
        v2f PB = __builtin_elementwise_fma(rB, PoB, PeB);
        v2f QB = __builtin_elementwise_fma(sB, QoB, QeB);

        v2f emA = EbA * PA;
        v2f evA = (EbA * EbA) * QA;
        v2f emB = EbB * PB;
        v2f evB = (EbB * EbB) * QB;

        // clamp per (b,o,i), BEFORE the i-sum
        v2f eps = {1e-6f, 1e-6f};
        v2f dA = __builtin_elementwise_fma(-emA, emA, evA);
        v2f dB = __builtin_elementwise_fma(-emB, emB, evB);
        evt += __builtin_elementwise_max(dA, eps);
        evt += __builtin_elementwise_max(dB, eps);
        emt += emA;
        emt += emB;
    }

    // ---- Phase C: reduce across waves, reusing xtile as scratch ----
    __syncthreads();                      // everyone done reading xtile
    float* red  = &xtile[0][0];           // em: [wave][b_local], 1024 floats
    float* redv = red + 1024;             // ev: [wave][b_local], 1024 floats
    red [wave * 128 + 2 * lane + 0] = emt.x;
    red [wave * 128 + 2 * lane + 1] = emt.y;
    redv[wave * 128 + 2 * lane + 0] = evt.x;
    redv[wave * 128 + 2 * lane + 1] = evt.y;
    __syncthreads();

    if (tid < 128) {
        float em = 0.f, ev = 0.f;
        #pragma unroll
        for (int w = 0; w < 8; ++w) {
            em += red [w * 128 + tid];
            ev += redv[w * 128 + tid];
        }
        const int bb = btile * 128 + tid;
        out[bb * ODIM + o]                = em;  // edge_means.sum(axis=2)
        out[BATCH * ODIM + bb * ODIM + o] = ev;  // edge_vars.sum(axis=2)
    }
}

extern "C" void kernel_launch(void* const* d_in, const int* in_sizes, int n_in,
                              void* d_out, int out_size, void* d_ws, size_t ws_size,
                              hipStream_t stream) {
    const float* x            = (const float*)d_in[0];
    const float* z            = (const float*)d_in[1];
    const float* q_mu         = (const float*)d_in[2];
    const float* q_log_var    = (const float*)d_in[3];
    const float* log_scale    = (const float*)d_in[4];
    const float* log_variance = (const float*)d_in[5];
    float* out = (float*)d_out;

    gpkan_fused_kernel<<<dim3((BATCH / 128) * ODIM), dim3(512), 0, stream>>>(
        x, z, q_mu, q_log_var, log_scale, log_variance, out);
}

// Round 12
// 81.795 us; speedup vs baseline: 1.0422x; 1.0241x over previous
//
#include <hip/hip_runtime.h>

#define BATCH 2048
#define ODIM 64
#define IDIM 64
#define MDIM 32

static constexpr float LOG2E = 1.4426950408889634f;

#if __has_builtin(__builtin_amdgcn_exp2f)
#define EXP2F(x) __builtin_amdgcn_exp2f(x)
#else
#define EXP2F(x) exp2f(x)
#endif

typedef float v2f __attribute__((ext_vector_type(2)));

// psi_m = A*2^{a(x-z_m)^2} = [A*2^{a z_m^2}] * Ebase * r^m,
//   Ebase = 2^{x(e1 x + e2)}, r = 2^{rc x};  e1=a, e2=-2a z0, rc=-2a dz.
// em_i = Ebase * P(r),  ev_i = Ebase^2 * Q(r^2); P,Q Horner (even/odd split).
//
// This round: coefficients live in SGPRs (s_load via wave-uniform address),
// so the Horner loop issues ONLY v_pk_fma — zero LDS-pipe traffic. LDS is
// used only for the tiny cross-wave reduction.

// Prep: blocks [0,256) -> coefficient quads {c1_2k, c2_2k, c1_2k+1, c2_2k+1};
// blocks [256,768) -> transpose x (B,I) -> xT (I,B).
__global__ __launch_bounds__(256) void prep_kernel(
    const float* __restrict__ x, const float* __restrict__ z,
    const float* __restrict__ q_mu, const float* __restrict__ q_log_var,
    const float* __restrict__ log_scale, const float* __restrict__ log_variance,
    float4* __restrict__ cmq, float4* __restrict__ aux, float* __restrict__ xT)
{
    const int bx = blockIdx.x;
    if (bx < 256) {
        int qt = bx * 256 + threadIdx.x;          // quad id in [0, O*I*16)
        int oi = qt >> 4;
        int k  = qt & 15;
        int g  = oi * MDIM + 2 * k;

        float ls   = log_scale[oi];
        float lv   = log_variance[oi];
        float ell  = fmaxf(expf(ls), 0.1f);
        float ell2 = ell * ell;
        float vk   = fmaxf(expf(lv), 1e-5f);
        float denom = ell2 + 1e-6f;               // x_var is constant EPS_XVAR
        float A    = vk * sqrtf(ell2 / denom);
        float a    = -0.5f * LOG2E / denom;       // base-2 exponent scale

        float qm0 = q_mu[g],     qm1 = q_mu[g + 1];
        float qv0 = fmaxf(expf(q_log_var[g]),     1e-5f);
        float qv1 = fmaxf(expf(q_log_var[g + 1]), 1e-5f);
        float zm0 = z[g],        zm1 = z[g + 1];
        float w0  = exp2f(a * zm0 * zm0);
        float w1  = exp2f(a * zm1 * zm1);

        float4 c;
        c.x = A * qm0 * w0;                          // c1[2k]
        c.y = A * A * (qv0 + qm0 * qm0) * w0 * w0;   // c2[2k]
        c.z = A * qm1 * w1;                          // c1[2k+1]
        c.w = A * A * (qv1 + qm1 * qm1) * w1 * w1;   // c2[2k+1]
        cmq[qt] = c;

        if (k == 0) {
            float z0 = z[oi * MDIM + 0];
            float z1 = z[oi * MDIM + 1];
            float dz = z1 - z0;
            aux[oi] = make_float4(a, -2.0f * a * z0, -2.0f * a * dz, 0.0f);
        }
    } else {
        int tid = (bx - 256) * 256 + threadIdx.x; // in [0, I*B)
        int i = tid >> 11;
        int b = tid & (BATCH - 1);
        xT[tid] = x[b * IDIM + i];
    }
}

// Main: block = one o x 128 b's (btile 0..15), 512 thr / 8 waves; wave w
// owns i in [8w, 8w+8); lane owns b-pair (2*lane, 2*lane+1) as <2 x float>.
__global__ __launch_bounds__(512, 8) void gpkan_main_kernel(
    const float* __restrict__ xT, const float4* __restrict__ cmq,
    const float4* __restrict__ aux, float* __restrict__ out)
{
    const int o     = blockIdx.x & (ODIM - 1);
    const int btile = blockIdx.x >> 6;                        // 0..15
    const int tid   = threadIdx.x;
    const int lane  = tid & 63;
    const int wave  = __builtin_amdgcn_readfirstlane(tid >> 6); // 0..7
    const int b0    = btile * 128 + 2 * lane;
    const int i0    = wave * 8;

    __shared__ float red[2][8][128];   // 8 KB, [em|ev][wave][b_local]

    // Preload x-pairs (coalesced dwordx2; latency hidden by 8 waves/SIMD).
    v2f xv[8];
    #pragma unroll
    for (int ii = 0; ii < 8; ++ii)
        xv[ii] = *(const v2f*)&xT[(size_t)(i0 + ii) * BATCH + b0];

    // Wave-uniform coefficient pointers -> compiler scalarizes to s_load.
    const float4* __restrict__ Cb = cmq + ((size_t)o * IDIM + i0) * 16;
    const float4* __restrict__ Ab = aux + o * IDIM + i0;

    v2f emt = {0.f, 0.f};
    v2f evt = {0.f, 0.f};

    #pragma unroll 1
    for (int ii = 0; ii < 8; ++ii) {
        const float4 Ax = Ab[ii];                 // s_load_dwordx4
        const v2f x2 = xv[ii];

        v2f e1 = {Ax.x, Ax.x}, e2 = {Ax.y, Ax.y}, rc = {Ax.z, Ax.z};

        v2f t = __builtin_elementwise_fma(e1, x2, e2) * x2;
        v2f Eb;
        Eb.x = EXP2F(t.x); Eb.y = EXP2F(t.y);
        v2f ur = rc * x2;
        v2f rr;
        rr.x = EXP2F(ur.x); rr.y = EXP2F(ur.y);

        v2f s = rr * rr;     // r^2  (P chains' arg)
        v2f u = s * s;       // r^4  (Q chains' arg)

        v2f Pe = {0.f, 0.f}, Po = {0.f, 0.f};
        v2f Qe = {0.f, 0.f}, Qo = {0.f, 0.f};

        const float4* C = Cb + ii * 16;           // wave-uniform -> s_load_dwordx16
        #pragma unroll
        for (int k = 15; k >= 0; --k) {
            float4 c = C[k];   // {c1_2k, c2_2k, c1_2k+1, c2_2k+1} in SGPRs
            v2f c1e = {c.x, c.x}, c2e = {c.y, c.y};
            v2f c1o = {c.z, c.z}, c2o = {c.w, c.w};
            Pe = __builtin_elementwise_fma(Pe, s, c1e);
            Po = __builtin_elementwise_fma(Po, s, c1o);
            Qe = __builtin_elementwise_fma(Qe, u, c2e);
            Qo = __builtin_elementwise_fma(Qo, u, c2o);
        }

        v2f P = __builtin_elementwise_fma(rr, Po, Pe);   // P(r)
        v2f Q = __builtin_elementwise_fma(s,  Qo, Qe);   // Q(r^2)

        v2f em_i = Eb * P;
        v2f ev_i = (Eb * Eb) * Q;

        // clamp per (b,o,i), BEFORE the i-sum
        v2f eps = {1e-6f, 1e-6f};
        v2f d   = __builtin_elementwise_fma(-em_i, em_i, ev_i);
        evt += __builtin_elementwise_max(d, eps);
        emt += em_i;
    }

    red[0][wave][2 * lane + 0] = emt.x;
    red[0][wave][2 * lane + 1] = emt.y;
    red[1][wave][2 * lane + 0] = evt.x;
    red[1][wave][2 * lane + 1] = evt.y;
    __syncthreads();

    if (tid < 256) {
        const int sel = tid >> 7;          // 0: means, 1: vars
        const int l   = tid & 127;
        float acc = 0.f;
        #pragma unroll
        for (int w = 0; w < 8; ++w) acc += red[sel][w][l];
        const int bb = btile * 128 + l;
        if (sel == 0) out[bb * ODIM + o] = acc;               // edge_means.sum(2)
        else          out[BATCH * ODIM + bb * ODIM + o] = acc; // edge_vars.sum(2)
    }
}

extern "C" void kernel_launch(void* const* d_in, const int* in_sizes, int n_in,
                              void* d_out, int out_size, void* d_ws, size_t ws_size,
                              hipStream_t stream) {
    const float* x            = (const float*)d_in[0];
    const float* z            = (const float*)d_in[1];
    const float* q_mu         = (const float*)d_in[2];
    const float* q_log_var    = (const float*)d_in[3];
    const float* log_scale    = (const float*)d_in[4];
    const float* log_variance = (const float*)d_in[5];
    float* out = (float*)d_out;

    // ws layout: cmq (O*I*16 float4 = 1 MiB) | aux (O*I float4 = 64 KiB)
    //          | xT (I*B f32 = 512 KiB)
    char* ws = (char*)d_ws;
    float4* cmq = (float4*)ws;
    float4* aux = (float4*)(ws + (size_t)ODIM * IDIM * 16 * sizeof(float4));
    float*  xT  = (float*)(ws + (size_t)ODIM * IDIM * 16 * sizeof(float4)
                              + (size_t)ODIM * IDIM * sizeof(float4));

    prep_kernel<<<dim3(768), dim3(256), 0, stream>>>(
        x, z, q_mu, q_log_var, log_scale, log_variance, cmq, aux, xT);
    gpkan_main_kernel<<<dim3((BATCH / 128) * ODIM), dim3(512), 0, stream>>>(
        xT, cmq, aux, out);
}

// Round 13
// 80.723 us; speedup vs baseline: 1.0560x; 1.0133x over previous
//
#include <hip/hip_runtime.h>

#define BATCH 2048
#define ODIM 64
#define IDIM 64
#define MDIM 32

static constexpr float LOG2E = 1.4426950408889634f;

#if __has_builtin(__builtin_amdgcn_exp2f)
#define EXP2F(x) __builtin_amdgcn_exp2f(x)
#else
#define EXP2F(x) exp2f(x)
#endif

typedef float v2f __attribute__((ext_vector_type(2)));

// psi_m = A*2^{a(x-z_m)^2} = [A*2^{a z_m^2}] * Ebase * r^m,
//   Ebase = 2^{x(e1 x + e2)}, r = 2^{rc x};  e1=a, e2=-2a z0, rc=-2a dz.
// em_i = Ebase * P(r),  ev_i = Ebase^2 * Q(r^2); P,Q Horner (even/odd split).
// Coefficients are wave-uniform -> s_load into SGPRs; Horner loop issues only
// v_pk_fma_f32 (VOP3P takes the SGPR broadcast directly). No LDS in hot loop.

// Prep: coefficient quads {c1_2k, c2_2k, c1_2k+1, c2_2k+1} + per-(o,i) aux.
__global__ __launch_bounds__(256) void prep_kernel(
    const float* __restrict__ z, const float* __restrict__ q_mu,
    const float* __restrict__ q_log_var, const float* __restrict__ log_scale,
    const float* __restrict__ log_variance,
    float4* __restrict__ cmq, float4* __restrict__ aux)
{
    int qt = blockIdx.x * 256 + threadIdx.x;  // quad id in [0, O*I*16)
    int oi = qt >> 4;
    int k  = qt & 15;
    int g  = oi * MDIM + 2 * k;

    float ls   = log_scale[oi];
    float lv   = log_variance[oi];
    float ell  = fmaxf(expf(ls), 0.1f);
    float ell2 = ell * ell;
    float vk   = fmaxf(expf(lv), 1e-5f);
    float denom = ell2 + 1e-6f;               // x_var is constant EPS_XVAR
    float A    = vk * sqrtf(ell2 / denom);
    float a    = -0.5f * LOG2E / denom;       // base-2 exponent scale

    float qm0 = q_mu[g],     qm1 = q_mu[g + 1];
    float qv0 = fmaxf(expf(q_log_var[g]),     1e-5f);
    float qv1 = fmaxf(expf(q_log_var[g + 1]), 1e-5f);
    float zm0 = z[g],        zm1 = z[g + 1];
    float w0  = exp2f(a * zm0 * zm0);
    float w1  = exp2f(a * zm1 * zm1);

    float4 c;
    c.x = A * qm0 * w0;                          // c1[2k]
    c.y = A * A * (qv0 + qm0 * qm0) * w0 * w0;   // c2[2k]
    c.z = A * qm1 * w1;                          // c1[2k+1]
    c.w = A * A * (qv1 + qm1 * qm1) * w1 * w1;   // c2[2k+1]
    cmq[qt] = c;

    if (k == 0) {
        float z0 = z[oi * MDIM + 0];
        float z1 = z[oi * MDIM + 1];
        float dz = z1 - z0;
        aux[oi] = make_float4(a, -2.0f * a * z0, -2.0f * a * dz, 0.0f);
    }
}

// Main: block = one o x 128 b's (btile 0..15), 512 thr / 8 waves; wave w
// owns i in [8w, 8w+8); lane owns b-pair (2*lane, 2*lane+1) as <2 x float>.
// x is read DIRECTLY (row-slices x[b][i0..i0+8) are 32B contiguous ->
// 4x global_load_dwordx4 per thread; L2-resident).
__global__ __launch_bounds__(512, 8) void gpkan_main_kernel(
    const float* __restrict__ x, const float4* __restrict__ cmq,
    const float4* __restrict__ aux, float* __restrict__ out)
{
    const int o     = blockIdx.x & (ODIM - 1);
    const int btile = blockIdx.x >> 6;                        // 0..15
    const int tid   = threadIdx.x;
    const int lane  = tid & 63;
    const int wave  = __builtin_amdgcn_readfirstlane(tid >> 6); // 0..7
    const int b0    = btile * 128 + 2 * lane;
    const int i0    = wave * 8;

    __shared__ float red[2][8][128];   // 8 KB, [em|ev][wave][b_local]

    // Load the two 8-float row slices for this lane's b-pair.
    const float4* pA = (const float4*)(x + (size_t)b0 * IDIM + i0);
    const float4* pB = (const float4*)(x + (size_t)(b0 + 1) * IDIM + i0);
    float4 a0 = pA[0], a1 = pA[1];
    float4 bb0 = pB[0], bb1 = pB[1];

    v2f xv[8];
    xv[0].x = a0.x; xv[0].y = bb0.x;
    xv[1].x = a0.y; xv[1].y = bb0.y;
    xv[2].x = a0.z; xv[2].y = bb0.z;
    xv[3].x = a0.w; xv[3].y = bb0.w;
    xv[4].x = a1.x; xv[4].y = bb1.x;
    xv[5].x = a1.y; xv[5].y = bb1.y;
    xv[6].x = a1.z; xv[6].y = bb1.z;
    xv[7].x = a1.w; xv[7].y = bb1.w;

    // Wave-uniform coefficient pointers -> compiler scalarizes to s_load.
    const float4* __restrict__ Cb = cmq + ((size_t)o * IDIM + i0) * 16;
    const float4* __restrict__ Ab = aux + o * IDIM + i0;

    v2f emt = {0.f, 0.f};
    v2f evt = {0.f, 0.f};

    #pragma unroll
    for (int ii = 0; ii < 8; ++ii) {
        const float4 Ax = Ab[ii];                 // s_load_dwordx4
        const v2f x2 = xv[ii];

        v2f e1 = {Ax.x, Ax.x}, e2 = {Ax.y, Ax.y}, rc = {Ax.z, Ax.z};

        v2f t = __builtin_elementwise_fma(e1, x2, e2) * x2;
        v2f Eb;
        Eb.x = EXP2F(t.x); Eb.y = EXP2F(t.y);
        v2f ur = rc * x2;
        v2f rr;
        rr.x = EXP2F(ur.x); rr.y = EXP2F(ur.y);

        v2f s = rr * rr;     // r^2  (P chains' arg)
        v2f u = s * s;       // r^4  (Q chains' arg)

        v2f Pe = {0.f, 0.f}, Po = {0.f, 0.f};
        v2f Qe = {0.f, 0.f}, Qo = {0.f, 0.f};

        const float4* C = Cb + ii * 16;           // wave-uniform -> s_load_dwordx16
        #pragma unroll
        for (int k = 15; k >= 0; --k) {
            float4 c = C[k];   // {c1_2k, c2_2k, c1_2k+1, c2_2k+1} in SGPRs
            v2f c1e = {c.x, c.x}, c2e = {c.y, c.y};
            v2f c1o = {c.z, c.z}, c2o = {c.w, c.w};
            Pe = __builtin_elementwise_fma(Pe, s, c1e);
            Po = __builtin_elementwise_fma(Po, s, c1o);
            Qe = __builtin_elementwise_fma(Qe, u, c2e);
            Qo = __builtin_elementwise_fma(Qo, u, c2o);
        }

        v2f P = __builtin_elementwise_fma(rr, Po, Pe);   // P(r)
        v2f Q = __builtin_elementwise_fma(s,  Qo, Qe);   // Q(r^2)

        v2f em_i = Eb * P;
        v2f ev_i = (Eb * Eb) * Q;

        // clamp per (b,o,i), BEFORE the i-sum
        v2f eps = {1e-6f, 1e-6f};
        v2f d   = __builtin_elementwise_fma(-em_i, em_i, ev_i);
        evt += __builtin_elementwise_max(d, eps);
        emt += em_i;
    }

    red[0][wave][2 * lane + 0] = emt.x;
    red[0][wave][2 * lane + 1] = emt.y;
    red[1][wave][2 * lane + 0] = evt.x;
    red[1][wave][2 * lane + 1] = evt.y;
    __syncthreads();

    if (tid < 256) {
        const int sel = tid >> 7;          // 0: means, 1: vars
        const int l   = tid & 127;
        float acc = 0.f;
        #pragma unroll
        for (int w = 0; w < 8; ++w) acc += red[sel][w][l];
        const int bb = btile * 128 + l;
        if (sel == 0) out[bb * ODIM + o] = acc;                // edge_means.sum(2)
        else          out[BATCH * ODIM + bb * ODIM + o] = acc; // edge_vars.sum(2)
    }
}

extern "C" void kernel_launch(void* const* d_in, const int* in_sizes, int n_in,
                              void* d_out, int out_size, void* d_ws, size_t ws_size,
                              hipStream_t stream) {
    const float* x            = (const float*)d_in[0];
    const float* z            = (const float*)d_in[1];
    const float* q_mu         = (const float*)d_in[2];
    const float* q_log_var    = (const float*)d_in[3];
    const float* log_scale    = (const float*)d_in[4];
    const float* log_variance = (const float*)d_in[5];
    float* out = (float*)d_out;

    // ws layout: cmq (O*I*16 float4 = 1 MiB) | aux (O*I float4 = 64 KiB)
    char* ws = (char*)d_ws;
    float4* cmq = (float4*)ws;
    float4* aux = (float4*)(ws + (size_t)ODIM * IDIM * 16 * sizeof(float4));

    prep_kernel<<<dim3(256), dim3(256), 0, stream>>>(
        z, q_mu, q_log_var, log_scale, log_variance, cmq, aux);
    gpkan_main_kernel<<<dim3((BATCH / 128) * ODIM), dim3(512), 0, stream>>>(
        x, cmq, aux, out);
}